// Round 17
// baseline (488.726 us; speedup 1.0000x reference)
//
#include <hip/hip_runtime.h>
#include <math.h>

#define Bsz 64
#define Tt  32
#define TTOT 35          // 32 encoder + 3 decode GRU steps
#define Dv  2048
#define Hd  1024
#define G3  3072
#define Vv  20000
#define ML  3
#define NTILE 1250       // 20000 / 16
#define FSTR 16          // flag stride (uints) -> one flag per 64B line

typedef __attribute__((ext_vector_type(8))) short bf16x8;
typedef __attribute__((ext_vector_type(4))) float f32x4;
typedef unsigned long long u64;
#define MFMA(a,b,c) __builtin_amdgcn_mfma_f32_16x16x32_bf16(a,b,c,0,0,0)

__device__ __forceinline__ short f2bf(float f) {
    union { float f; unsigned u; } v; v.f = f;
    unsigned r = v.u + 0x7fffu + ((v.u >> 16) & 1u);
    return (short)(r >> 16);
}
__device__ __forceinline__ void cvt8(const float* __restrict__ s,
                                     short* __restrict__ d) {
    float4 x = *(const float4*)s;
    float4 y = *(const float4*)(s + 4);
    bf16x8 o;
    o[0]=f2bf(x.x); o[1]=f2bf(x.y); o[2]=f2bf(x.z); o[3]=f2bf(x.w);
    o[4]=f2bf(y.x); o[5]=f2bf(y.y); o[6]=f2bf(y.z); o[7]=f2bf(y.w);
    *(bf16x8*)d = o;
}
__device__ __forceinline__ bf16x8 pack8(const float* __restrict__ s) {
    float4 x = *(const float4*)s;
    float4 y = *(const float4*)(s + 4);
    bf16x8 o;
    o[0]=f2bf(x.x); o[1]=f2bf(x.y); o[2]=f2bf(x.z); o[3]=f2bf(x.w);
    o[4]=f2bf(y.x); o[5]=f2bf(y.y); o[6]=f2bf(y.z); o[7]=f2bf(y.w);
    return o;
}
__device__ __forceinline__ bf16x8 pack2(const float4& x, const float4& y) {
    bf16x8 o;
    o[0]=f2bf(x.x); o[1]=f2bf(x.y); o[2]=f2bf(x.z); o[3]=f2bf(x.w);
    o[4]=f2bf(y.x); o[5]=f2bf(y.y); o[6]=f2bf(y.z); o[7]=f2bf(y.w);
    return o;
}

// One wave polls 64 per-block flags (padded: one per 64B line).
__device__ __forceinline__ void poll_flags(const unsigned* fl, unsigned tgt) {
    const int lane = threadIdx.x & 63;
    const unsigned* p = &fl[lane * FSTR];
    unsigned f = __hip_atomic_load(p, __ATOMIC_RELAXED, __HIP_MEMORY_SCOPE_AGENT);
    while (!__all((int)(f >= tgt))) {
        __builtin_amdgcn_s_sleep(2);
        f = __hip_atomic_load(p, __ATOMIC_RELAXED, __HIP_MEMORY_SCOPE_AGENT);
    }
}

// ---------------------------------------------------------------------------
// fp32 -> bf16 conversion: vid + W_ih1 (mega roles convert their own slices).
// ---------------------------------------------------------------------------
__global__ __launch_bounds__(256)
void cvt2(const float* __restrict__ vid,  short* __restrict__ vid_bf,
          const float* __restrict__ Wih1, short* __restrict__ Wih1_bf)
{
    const long b0 = 524288;            // vid   2048*2048/8
    const long b1 = b0 + 786432;       // W_ih1 3072*2048/8
    for (long i = (long)blockIdx.x * 256 + threadIdx.x; i < b1;
         i += (long)gridDim.x * 256) {
        if (i < b0) cvt8(vid + i * 8, vid_bf + i * 8);
        else { const long q = i - b0; cvt8(Wih1 + q * 8, Wih1_bf + q * 8); }
    }
}

// ---------------------------------------------------------------------------
// xp1 GEMM + W_obj/W_rel conversion hidden under it.
// Blocks 0..383: 128x128 GEMM tiles (global_load_lds staging into
// fragment-linear LDS; per-lane global address carries the permutation).
// Blocks 384..703: grid-stride fp32->bf16 conversion of W_obj+W_rel —
// the GEMM is compute-bound with HBM nearly idle, so the 240 MB stream
// rides for ~free. Writes xp1 T-MAJOR.
// ---------------------------------------------------------------------------
__global__ __launch_bounds__(256)
void gemm_xp1(const short* __restrict__ vid_bf,
              const short* __restrict__ Wih1_bf,
              const float* __restrict__ b_ih1,
              float* __restrict__ xp1,
              const float* __restrict__ Wobj, const float* __restrict__ Wrel,
              short* __restrict__ Wobj_bf, short* __restrict__ Wrel_bf,
              int do_cvt)
{
    __shared__ __align__(16) short As[8 * 64 * 8];   // 8 KB, fragment order
    __shared__ __align__(16) short Bs[8 * 64 * 8];
    const int tid = threadIdx.x;

    if (blockIdx.x >= 384) {
        if (do_cvt) {
            const int cb = blockIdx.x - 384;           // 0..319
            const long NC = (long)Vv * Hd / 8;         // 2,560,000 per matrix
            for (long i = (long)cb * 256 + tid; i < 2 * NC; i += 320L * 256) {
                if (i < NC) cvt8(Wobj + i * 8, Wobj_bf + i * 8);
                else { const long q = i - NC; cvt8(Wrel + q * 8, Wrel_bf + q * 8); }
            }
        }
        return;
    }

    const int w = tid >> 6, l = tid & 63;
    const int wm = w >> 1, wn = w & 1;
    const int lr = l & 15, lg = l >> 4;
    const int m0 = (blockIdx.x / 24) * 128, n0 = (blockIdx.x % 24) * 128;

    f32x4 acc[4][4] = {};

    for (int k0 = 0; k0 < Dv; k0 += 32) {
        #pragma unroll
        for (int i = 0; i < 2; ++i) {
            const int q  = i * 256 + tid;
            const int r  = ((q >> 6) << 4) | (q & 15);
            const int sc = (q >> 4) & 3;
            const int m  = m0 + r;
            const int arow = (m & 63) * Tt + (m >> 6);   // t-major -> vid row
            __builtin_amdgcn_global_load_lds(
                (const void*)(vid_bf + (size_t)arow * Dv + k0 + sc * 8),
                (void*)(As + q * 8), 16, 0, 0);
            __builtin_amdgcn_global_load_lds(
                (const void*)(Wih1_bf + (size_t)(n0 + r) * Dv + k0 + sc * 8),
                (void*)(Bs + q * 8), 16, 0, 0);
        }
        __syncthreads();
        bf16x8 af[4], bfr[4];
        #pragma unroll
        for (int mt = 0; mt < 4; ++mt) {
            af[mt]  = *(const bf16x8*)(As + ((wm * 4 + mt) * 64 + l) * 8);
            bfr[mt] = *(const bf16x8*)(Bs + ((wn * 4 + mt) * 64 + l) * 8);
        }
        #pragma unroll
        for (int mt = 0; mt < 4; ++mt)
            #pragma unroll
            for (int nt = 0; nt < 4; ++nt)
                acc[mt][nt] = MFMA(af[mt], bfr[nt], acc[mt][nt]);
        __syncthreads();
    }

    #pragma unroll
    for (int mt = 0; mt < 4; ++mt)
        #pragma unroll
        for (int nt = 0; nt < 4; ++nt)
            #pragma unroll
            for (int v = 0; v < 4; ++v) {
                const int m = m0 + wm * 64 + mt * 16 + lg * 4 + v;
                const int n = n0 + wn * 64 + nt * 16 + lr;
                xp1[(size_t)m * G3 + n] = acc[mt][nt][v] + b_ih1[n];
            }
}

// ---------------------------------------------------------------------------
// MEGAKERNEL (r16 form — best known): encoder pipeline + decode GRU steps.
// 192 blocks = 3 roles x 64. Block-wide one-wave flag poll; padded flags.
// ---------------------------------------------------------------------------
__global__ __launch_bounds__(256, 1)
void mega(const float* __restrict__ xp1, const float* __restrict__ b_ih1,
          const float* __restrict__ Whh1f, const float* __restrict__ b_hh1,
          const float* __restrict__ Wih2f, const float* __restrict__ b_ih2,
          const float* __restrict__ Whh2f, const float* __restrict__ b_hh2,
          short* __restrict__ out1h,   // (36,64,1024) bf16, slot0 = 0
          float* __restrict__ xp2s,    // (35,64,3072) fp32
          short* __restrict__ h2h,     // (36,64,1024) bf16, slot0 = 0
          unsigned* __restrict__ flags1, unsigned* __restrict__ flagsP,
          unsigned* __restrict__ flags2)
{
    __shared__ __align__(16) short Wl[4 * 3 * 8 * 64 * 8];   // 98304 B
    __shared__ __align__(16) float xch[4][4][3][256];        // 49152 B
    __shared__ __align__(16) short hstage[64][16];           // 2048 B
    const int tid = threadIdx.x;
    const int w  = tid >> 6;
    const int l  = tid & 63;
    const int lr = l & 15, lg = l >> 4;
    const int role = blockIdx.x >> 6;         // 0=GRU1, 1=proj, 2=GRU2
    const int k    = blockIdx.x & 63;
    const int j0 = k * 16;
    const int j  = j0 + lr;

    const float* Wf = (role == 0) ? Whh1f : (role == 1) ? Wih2f : Whh2f;
    const int ldw   = (role == 1) ? (Hd + 512) : Hd;
    const float* bias = (role == 0) ? b_hh1 : (role == 1) ? b_ih2 : b_hh2;

    // stage W slice into LDS, fp32 -> bf16 in-register, fragment-linear
    #pragma unroll
    for (int g = 0; g < 3; ++g)
        #pragma unroll
        for (int ks = 0; ks < 8; ++ks) {
            const float* src = Wf + (size_t)(g * Hd + j) * ldw + w * 256 + ks * 32 + lg * 8;
            *(bf16x8*)(Wl + ((((w * 3 + g) * 8 + ks) * 64) + l) * 8) = pack8(src);
        }

    const float b0 = bias[j], b1 = bias[Hd + j], b2 = bias[2 * Hd + j];
    short* Ab = (role == 2) ? h2h : out1h;

    float bxr = 0.f, bxz = 0.f, bxn = 0.f;
    float hp[4] = {0.f, 0.f, 0.f, 0.f};
    float xr[4], xz[4], xn[4];
    if (role == 0) {
        bxr = b_ih1[j]; bxz = b_ih1[Hd + j]; bxn = b_ih1[2 * Hd + j];
        #pragma unroll
        for (int v = 0; v < 4; ++v) {        // prefetch xp for t=0
            const int b = w * 16 + lg * 4 + v;
            const float* xrow = xp1 + (size_t)b * G3;    // t=0 row = b
            xr[v] = xrow[j]; xz[v] = xrow[Hd + j]; xn[v] = xrow[2 * Hd + j];
        }
    }
    __syncthreads();   // Wl ready

    for (int t = 0; t < TTOT; ++t) {
        if (role == 0)      { if (w == 0) poll_flags(flags1, (unsigned)t); }
        else if (role == 1) { if (w == 0) poll_flags(flags1, (unsigned)(t + 1)); }
        else {
            if (w == 0)      poll_flags(flagsP, (unsigned)(t + 1));
            else if (w == 1) poll_flags(flags2, (unsigned)t);
        }
        __syncthreads();
        asm volatile("" ::: "memory");

        const short* hin = Ab + (size_t)(role == 1 ? t + 1 : t) * (64 * Hd);
        bf16x8 A[4][8];
        #pragma unroll
        for (int mt = 0; mt < 4; ++mt)
            #pragma unroll
            for (int ks = 0; ks < 8; ++ks)
                A[mt][ks] = *(const bf16x8*)(hin + (size_t)(mt * 16 + lr) * Hd
                                             + w * 256 + ks * 32 + lg * 8);
        if (role == 2) {
            #pragma unroll
            for (int v = 0; v < 4; ++v) {
                const int b = w * 16 + lg * 4 + v;
                const float* xrow = xp2s + ((size_t)t * 64 + b) * G3;
                xr[v] = xrow[j]; xz[v] = xrow[Hd + j]; xn[v] = xrow[2 * Hd + j];
            }
        }

        f32x4 acc[4][3] = {};
        #pragma unroll
        for (int ks = 0; ks < 8; ++ks) {
            bf16x8 B0 = *(const bf16x8*)(Wl + ((((w * 3 + 0) * 8 + ks) * 64) + l) * 8);
            bf16x8 B1 = *(const bf16x8*)(Wl + ((((w * 3 + 1) * 8 + ks) * 64) + l) * 8);
            bf16x8 B2 = *(const bf16x8*)(Wl + ((((w * 3 + 2) * 8 + ks) * 64) + l) * 8);
            #pragma unroll
            for (int mt = 0; mt < 4; ++mt) {
                acc[mt][0] = MFMA(A[mt][ks], B0, acc[mt][0]);
                acc[mt][1] = MFMA(A[mt][ks], B1, acc[mt][1]);
                acc[mt][2] = MFMA(A[mt][ks], B2, acc[mt][2]);
            }
        }

        #pragma unroll
        for (int mt = 0; mt < 4; ++mt)
            #pragma unroll
            for (int g = 0; g < 3; ++g)
                *(f32x4*)&xch[w][mt][g][l * 4] = acc[mt][g];
        __syncthreads();
        f32x4 tot[3];
        #pragma unroll
        for (int g = 0; g < 3; ++g) {
            f32x4 t0 = *(const f32x4*)&xch[0][w][g][l * 4];
            f32x4 t1 = *(const f32x4*)&xch[1][w][g][l * 4];
            f32x4 t2 = *(const f32x4*)&xch[2][w][g][l * 4];
            f32x4 t3 = *(const f32x4*)&xch[3][w][g][l * 4];
            tot[g] = (t0 + t1) + (t2 + t3);
        }

        if (role == 1) {
            const float bg[3] = {b0, b1, b2};
            #pragma unroll
            for (int v = 0; v < 4; ++v) {
                const int b = w * 16 + lg * 4 + v;
                #pragma unroll
                for (int g = 0; g < 3; ++g) {
                    union { float f; unsigned u; } cv;
                    cv.f = tot[g][v] + bg[g];
                    __hip_atomic_store(
                        (unsigned*)(xp2s + ((size_t)t * 64 + b) * G3 + g * Hd + j),
                        cv.u, __ATOMIC_RELAXED, __HIP_MEMORY_SCOPE_AGENT);
                }
            }
            __syncthreads();
        } else {
            #pragma unroll
            for (int v = 0; v < 4; ++v) {
                const int b = w * 16 + lg * 4 + v;
                const float rg = 1.f / (1.f + __expf(-(xr[v] + tot[0][v] + b0)));
                const float zg = 1.f / (1.f + __expf(-(xz[v] + tot[1][v] + b1)));
                const float ng = tanhf(xn[v] + rg * (tot[2][v] + b2));
                const float hv = (1.f - zg) * ng + zg * hp[v];
                hp[v] = hv;
                hstage[b][lr] = f2bf(hv);
            }
            if (role == 0) {   // prefetch next round's xp (xp1 static)
                if (t + 1 < Tt) {
                    #pragma unroll
                    for (int v = 0; v < 4; ++v) {
                        const int b = w * 16 + lg * 4 + v;
                        const float* xrow = xp1 + (size_t)((t + 1) * 64 + b) * G3;
                        xr[v] = xrow[j]; xz[v] = xrow[Hd + j]; xn[v] = xrow[2 * Hd + j];
                    }
                } else {
                    #pragma unroll
                    for (int v = 0; v < 4; ++v) { xr[v]=bxr; xz[v]=bxz; xn[v]=bxn; }
                }
            }
            __syncthreads();
            {
                const int b = tid >> 2, part = tid & 3;
                const u64 pv = *(const u64*)&hstage[b][part * 4];
                __hip_atomic_store(
                    (u64*)(Ab + (size_t)(t + 1) * (64 * Hd) + b * Hd + j0 + part * 4),
                    pv, __ATOMIC_RELAXED, __HIP_MEMORY_SCOPE_AGENT);
            }
            __syncthreads();
        }

        if (tid == 0) {
            unsigned* fl = (role == 0) ? flags1 : (role == 1) ? flagsP : flags2;
            __hip_atomic_store(&fl[k * FSTR], (unsigned)(t + 1),
                               __ATOMIC_RELAXED, __HIP_MEMORY_SCOPE_AGENT);
        }
    }
}

// ---------------------------------------------------------------------------
// Logits GEMM v5: WBF16 path reads pre-converted bf16 W (80 MB total, no
// in-register pack, ring 4 / chunk 2 -> register-lean, 3 waves/SIMD).
// fp32 fallback = r13 form. Blocks 0..312: one W_obj pass computes decode
// steps 0 AND 2. Blocks 313..625: W_rel pass for step 1.
// ---------------------------------------------------------------------------
template<bool WBF16>
__global__ __launch_bounds__(256)
void logits_dual(const short* __restrict__ h2h,
                 const void* __restrict__ Wobj, const float* __restrict__ bobj,
                 const void* __restrict__ Wrel, const float* __restrict__ brel,
                 float* __restrict__ logits3)
{
    const int tid = threadIdx.x;
    const int w = tid >> 6, l = tid & 63;
    const int lr = l & 15, lg = l >> 4;
    const bool dual = blockIdx.x < 313;
    const int nb = dual ? blockIdx.x : blockIdx.x - 313;
    const int tile = nb * 4 + w;
    if (tile >= NTILE) return;
    const int n0 = tile * 16;
    const void* Wo = dual ? Wobj : Wrel;
    const float* bo = dual ? bobj : brel;
    const short* h0 = dual ? (h2h + (size_t)33 * 64 * Hd)
                           : (h2h + (size_t)34 * 64 * Hd);
    const short* hC = h2h + (size_t)35 * 64 * Hd;
    const short* abase = h0 + (size_t)lr * Hd + lg * 8;
    const short* cbase = hC + (size_t)lr * Hd + lg * 8;

    f32x4 accA[4] = {}, accC[4] = {};

    if constexpr (WBF16) {
        const short* wbase = (const short*)Wo + (size_t)(n0 + lr) * Hd + lg * 8;
        bf16x8 wr[4];
        #pragma unroll
        for (int i = 0; i < 4; ++i) wr[i] = *(const bf16x8*)(wbase + i * 32);

        #pragma unroll
        for (int kc = 0; kc < 16; ++kc) {
            bf16x8 Ach[4][2], Cch[4][2];
            #pragma unroll
            for (int u = 0; u < 2; ++u) {
                const int ks = kc * 2 + u;
                #pragma unroll
                for (int mt = 0; mt < 4; ++mt)
                    Ach[mt][u] = *(const bf16x8*)(abase + (size_t)(mt * 16) * Hd + ks * 32);
            }
            if (dual) {
                #pragma unroll
                for (int u = 0; u < 2; ++u) {
                    const int ks = kc * 2 + u;
                    #pragma unroll
                    for (int mt = 0; mt < 4; ++mt)
                        Cch[mt][u] = *(const bf16x8*)(cbase + (size_t)(mt * 16) * Hd + ks * 32);
                }
            }
            #pragma unroll
            for (int u = 0; u < 2; ++u) {
                const int ks = kc * 2 + u;
                const int bi = ks & 3;
                const bf16x8 wv = wr[bi];
                if (ks < 28) wr[bi] = *(const bf16x8*)(wbase + (ks + 4) * 32);
                #pragma unroll
                for (int mt = 0; mt < 4; ++mt) {
                    accA[mt] = MFMA(Ach[mt][u], wv, accA[mt]);
                    if (dual) accC[mt] = MFMA(Cch[mt][u], wv, accC[mt]);
                }
            }
        }
    } else {
        const float* wbase = (const float*)Wo + (size_t)(n0 + lr) * Hd + lg * 8;
        float4 wx[8], wy[8];
        #pragma unroll
        for (int i = 0; i < 8; ++i) {
            wx[i] = *(const float4*)(wbase + i * 32);
            wy[i] = *(const float4*)(wbase + i * 32 + 4);
        }
        #pragma unroll
        for (int kc = 0; kc < 8; ++kc) {
            bf16x8 Ach[4][4], Cch[4][4];
            #pragma unroll
            for (int u = 0; u < 4; ++u) {
                const int ks = kc * 4 + u;
                #pragma unroll
                for (int mt = 0; mt < 4; ++mt)
                    Ach[mt][u] = *(const bf16x8*)(abase + (size_t)(mt * 16) * Hd + ks * 32);
            }
            if (dual) {
                #pragma unroll
                for (int u = 0; u < 4; ++u) {
                    const int ks = kc * 4 + u;
                    #pragma unroll
                    for (int mt = 0; mt < 4; ++mt)
                        Cch[mt][u] = *(const bf16x8*)(cbase + (size_t)(mt * 16) * Hd + ks * 32);
                }
            }
            #pragma unroll
            for (int u = 0; u < 4; ++u) {
                const int ks = kc * 4 + u;
                const int bi = ks & 7;
                const bf16x8 wv = pack2(wx[bi], wy[bi]);
                if (ks < 24) {
                    wx[bi] = *(const float4*)(wbase + (ks + 8) * 32);
                    wy[bi] = *(const float4*)(wbase + (ks + 8) * 32 + 4);
                }
                #pragma unroll
                for (int mt = 0; mt < 4; ++mt) {
                    accA[mt] = MFMA(Ach[mt][u], wv, accA[mt]);
                    if (dual) accC[mt] = MFMA(Cch[mt][u], wv, accC[mt]);
                }
            }
        }
    }

    const float bn = bo[n0 + lr];
    float* lg0 = logits3 + (size_t)(dual ? 0 : 1) * 64 * Vv;
    float* lg2 = logits3 + (size_t)2 * 64 * Vv;
    #pragma unroll
    for (int mt = 0; mt < 4; ++mt)
        #pragma unroll
        for (int v = 0; v < 4; ++v) {
            const size_t row = (size_t)(mt * 16 + lg * 4 + v) * Vv + n0 + lr;
            lg0[row] = accA[mt][v] + bn;
            if (dual) lg2[row] = accC[mt][v] + bn;
        }
}

// ---------------------------------------------------------------------------
// Row log-softmax for all 3 steps: grid 192 = (step, batch).
// ---------------------------------------------------------------------------
__global__ __launch_bounds__(256)
void log_softmax_all(const float* __restrict__ logits3, float* __restrict__ out)
{
    __shared__ float red[4];
    const int step = blockIdx.x >> 6;
    const int b    = blockIdx.x & 63;
    const int tid  = threadIdx.x;
    const float* row = logits3 + ((size_t)step * 64 + b) * Vv;

    float m = -1e30f;
    for (int v = tid; v < Vv; v += 256) m = fmaxf(m, row[v]);
    #pragma unroll
    for (int off = 32; off > 0; off >>= 1) m = fmaxf(m, __shfl_down(m, off, 64));
    if ((tid & 63) == 0) red[tid >> 6] = m;
    __syncthreads();
    m = fmaxf(fmaxf(red[0], red[1]), fmaxf(red[2], red[3]));
    __syncthreads();

    float s = 0.f;
    for (int v = tid; v < Vv; v += 256) s += expf(row[v] - m);
    #pragma unroll
    for (int off = 32; off > 0; off >>= 1) s += __shfl_down(s, off, 64);
    if ((tid & 63) == 0) red[tid >> 6] = s;
    __syncthreads();
    s = red[0] + red[1] + red[2] + red[3];
    const float lse = m + logf(s);

    float* orow = out + ((size_t)b * ML + step) * Vv;
    for (int v = tid; v < Vv; v += 256) orow[v] = row[v] - lse;
}

// ---------------------------------------------------------------------------
extern "C" void kernel_launch(void* const* d_in, const int* in_sizes, int n_in,
                              void* d_out, int out_size, void* d_ws, size_t ws_size,
                              hipStream_t stream)
{
    (void)in_sizes; (void)n_in; (void)out_size;
    const float* vid   = (const float*)d_in[0];
    const float* W_ih1 = (const float*)d_in[1];
    const float* W_hh1 = (const float*)d_in[2];
    const float* b_ih1 = (const float*)d_in[3];
    const float* b_hh1 = (const float*)d_in[4];
    const float* W_ih2 = (const float*)d_in[5];   // (3072,1536); cols 0..1023 used
    const float* W_hh2 = (const float*)d_in[6];
    const float* b_ih2 = (const float*)d_in[7];
    const float* b_hh2 = (const float*)d_in[8];
    const float* W_obj = (const float*)d_in[9];
    const float* b_obj = (const float*)d_in[10];
    const float* W_rel = (const float*)d_in[11];
    const float* b_rel = (const float*)d_in[12];
    float* out = (float*)d_out;

    // workspace carve-up (~180 MB with bf16 W_obj/W_rel)
    char* p = (char*)d_ws;
    short* vid_bf   = (short*)p; p += (size_t)2048 * Dv * 2;        // 8.0 MB
    short* Wih1_bf  = (short*)p; p += (size_t)G3 * Dv * 2;          // 12.6 MB
    unsigned int* flg = (unsigned int*)p; p += 16384;               // padded flags
    short* out1h  = (short*)p; p += (size_t)36 * 64 * Hd * 2;       // 4.7 MB
    short* h2h    = (short*)p; p += (size_t)36 * 64 * Hd * 2;       // 4.7 MB
    float* xp1    = (float*)p; p += (size_t)2048 * G3 * 4;          // 25.2 MB (t-major)
    float* xp2s   = (float*)p; p += (size_t)TTOT * 64 * G3 * 4;     // 27.5 MB
    float* logits3= (float*)p; p += (size_t)ML * 64 * Vv * 4;       // 15.4 MB
    short* Wobj_bf = (short*)p; p += (size_t)Vv * Hd * 2;           // 41.0 MB
    short* Wrel_bf = (short*)p; p += (size_t)Vv * Hd * 2;           // 41.0 MB
    const int use_bf = ((size_t)(p - (char*)d_ws) <= ws_size) ? 1 : 0;

    unsigned* flags1 = flg;                 // 64 flags x stride 16
    unsigned* flagsP = flg + 1024;
    unsigned* flags2 = flg + 2048;

    hipMemsetAsync(flg, 0, 16384, stream);
    hipMemsetAsync(out1h, 0, (size_t)64 * Hd * 2, stream);   // slot 0 = h1(-1)=0
    hipMemsetAsync(h2h,   0, (size_t)64 * Hd * 2, stream);   // slot 0 = h2(-1)=0

    // convert vid + W_ih1 (recurrent/projection weights converted in mega)
    cvt2<<<1280, 256, 0, stream>>>(vid, vid_bf, W_ih1, Wih1_bf);

    // xp1 GEMM (blocks 0..383) + W_obj/W_rel bf16 conversion (384..703)
    gemm_xp1<<<704, 256, 0, stream>>>(vid_bf, Wih1_bf, b_ih1, xp1,
                                      W_obj, W_rel, Wobj_bf, Wrel_bf, use_bf);

    // megakernel: encoder pipeline + decode GRU steps (192 blocks)
    mega<<<192, 256, 0, stream>>>(
        xp1, b_ih1, W_hh1, b_hh1, W_ih2, b_ih2, W_hh2, b_hh2,
        out1h, xp2s, h2h, flags1, flagsP, flags2);

    // logits for all 3 decode steps (one W_obj pass covers steps 0 and 2)
    if (use_bf)
        logits_dual<true><<<626, 256, 0, stream>>>(
            h2h, (const void*)Wobj_bf, b_obj, (const void*)Wrel_bf, b_rel, logits3);
    else
        logits_dual<false><<<626, 256, 0, stream>>>(
            h2h, (const void*)W_obj, b_obj, (const void*)W_rel, b_rel, logits3);

    // log-softmax -> d_out
    log_softmax_all<<<192, 256, 0, stream>>>(logits3, out);
}

// Round 18
// 455.694 us; speedup vs baseline: 1.0725x; 1.0725x over previous
//
#include <hip/hip_runtime.h>
#include <math.h>

#define Bsz 64
#define Tt  32
#define TTOT 35          // 32 encoder + 3 decode GRU steps
#define Dv  2048
#define Hd  1024
#define G3  3072
#define Vv  20000
#define ML  3
#define NTILE 1250       // 20000 / 16
#define FSTR 16          // flag stride (uints) -> one flag per 64B line

typedef __attribute__((ext_vector_type(8))) short bf16x8;
typedef __attribute__((ext_vector_type(4))) float f32x4;
typedef unsigned long long u64;
#define MFMA(a,b,c) __builtin_amdgcn_mfma_f32_16x16x32_bf16(a,b,c,0,0,0)

__device__ __forceinline__ short f2bf(float f) {
    union { float f; unsigned u; } v; v.f = f;
    unsigned r = v.u + 0x7fffu + ((v.u >> 16) & 1u);
    return (short)(r >> 16);
}
__device__ __forceinline__ void cvt8(const float* __restrict__ s,
                                     short* __restrict__ d) {
    float4 x = *(const float4*)s;
    float4 y = *(const float4*)(s + 4);
    bf16x8 o;
    o[0]=f2bf(x.x); o[1]=f2bf(x.y); o[2]=f2bf(x.z); o[3]=f2bf(x.w);
    o[4]=f2bf(y.x); o[5]=f2bf(y.y); o[6]=f2bf(y.z); o[7]=f2bf(y.w);
    *(bf16x8*)d = o;
}
__device__ __forceinline__ bf16x8 pack8(const float* __restrict__ s) {
    float4 x = *(const float4*)s;
    float4 y = *(const float4*)(s + 4);
    bf16x8 o;
    o[0]=f2bf(x.x); o[1]=f2bf(x.y); o[2]=f2bf(x.z); o[3]=f2bf(x.w);
    o[4]=f2bf(y.x); o[5]=f2bf(y.y); o[6]=f2bf(y.z); o[7]=f2bf(y.w);
    return o;
}
__device__ __forceinline__ bf16x8 pack2(const float4& x, const float4& y) {
    bf16x8 o;
    o[0]=f2bf(x.x); o[1]=f2bf(x.y); o[2]=f2bf(x.z); o[3]=f2bf(x.w);
    o[4]=f2bf(y.x); o[5]=f2bf(y.y); o[6]=f2bf(y.z); o[7]=f2bf(y.w);
    return o;
}

// One wave polls 64 per-block flags (padded: one per 64B line).
__device__ __forceinline__ void poll_flags(const unsigned* fl, unsigned tgt) {
    const int lane = threadIdx.x & 63;
    const unsigned* p = &fl[lane * FSTR];
    unsigned f = __hip_atomic_load(p, __ATOMIC_RELAXED, __HIP_MEMORY_SCOPE_AGENT);
    while (!__all((int)(f >= tgt))) {
        __builtin_amdgcn_s_sleep(2);
        f = __hip_atomic_load(p, __ATOMIC_RELAXED, __HIP_MEMORY_SCOPE_AGENT);
    }
}

// ---------------------------------------------------------------------------
// fp32 -> bf16 conversion: vid + W_ih1 (mega roles convert their own slices).
// ---------------------------------------------------------------------------
__global__ __launch_bounds__(256)
void cvt2(const float* __restrict__ vid,  short* __restrict__ vid_bf,
          const float* __restrict__ Wih1, short* __restrict__ Wih1_bf)
{
    const long b0 = 524288;            // vid   2048*2048/8
    const long b1 = b0 + 786432;       // W_ih1 3072*2048/8
    for (long i = (long)blockIdx.x * 256 + threadIdx.x; i < b1;
         i += (long)gridDim.x * 256) {
        if (i < b0) cvt8(vid + i * 8, vid_bf + i * 8);
        else { const long q = i - b0; cvt8(Wih1 + q * 8, Wih1_bf + q * 8); }
    }
}

// ---------------------------------------------------------------------------
// xp1 GEMM (r16 form): global_load_lds staging into fragment-linear LDS;
// per-lane global address carries the permutation. Writes xp1 T-MAJOR.
// ---------------------------------------------------------------------------
__global__ __launch_bounds__(256)
void gemm_xp1(const short* __restrict__ vid_bf,
              const short* __restrict__ Wih1_bf,
              const float* __restrict__ b_ih1,
              float* __restrict__ xp1)
{
    __shared__ __align__(16) short As[8 * 64 * 8];   // 8 KB, fragment order
    __shared__ __align__(16) short Bs[8 * 64 * 8];
    const int tid = threadIdx.x;
    const int w = tid >> 6, l = tid & 63;
    const int wm = w >> 1, wn = w & 1;
    const int lr = l & 15, lg = l >> 4;
    const int m0 = blockIdx.y * 128, n0 = blockIdx.x * 128;

    f32x4 acc[4][4] = {};

    for (int k0 = 0; k0 < Dv; k0 += 32) {
        #pragma unroll
        for (int i = 0; i < 2; ++i) {
            const int q  = i * 256 + tid;
            const int r  = ((q >> 6) << 4) | (q & 15);
            const int sc = (q >> 4) & 3;
            const int m  = m0 + r;
            const int arow = (m & 63) * Tt + (m >> 6);   // t-major -> vid row
            __builtin_amdgcn_global_load_lds(
                (const void*)(vid_bf + (size_t)arow * Dv + k0 + sc * 8),
                (void*)(As + q * 8), 16, 0, 0);
            __builtin_amdgcn_global_load_lds(
                (const void*)(Wih1_bf + (size_t)(n0 + r) * Dv + k0 + sc * 8),
                (void*)(Bs + q * 8), 16, 0, 0);
        }
        __syncthreads();
        bf16x8 af[4], bfr[4];
        #pragma unroll
        for (int mt = 0; mt < 4; ++mt) {
            af[mt]  = *(const bf16x8*)(As + ((wm * 4 + mt) * 64 + l) * 8);
            bfr[mt] = *(const bf16x8*)(Bs + ((wn * 4 + mt) * 64 + l) * 8);
        }
        #pragma unroll
        for (int mt = 0; mt < 4; ++mt)
            #pragma unroll
            for (int nt = 0; nt < 4; ++nt)
                acc[mt][nt] = MFMA(af[mt], bfr[nt], acc[mt][nt]);
        __syncthreads();
    }

    #pragma unroll
    for (int mt = 0; mt < 4; ++mt)
        #pragma unroll
        for (int nt = 0; nt < 4; ++nt)
            #pragma unroll
            for (int v = 0; v < 4; ++v) {
                const int m = m0 + wm * 64 + mt * 16 + lg * 4 + v;
                const int n = n0 + wn * 64 + nt * 16 + lr;
                xp1[(size_t)m * G3 + n] = acc[mt][nt][v] + b_ih1[n];
            }
}

// ---------------------------------------------------------------------------
// MEGAKERNEL: encoder pipeline + decode GRU steps + hidden W_obj/W_rel
// conversion. 256 blocks: roles 0-2 (0..191) as r16; role 3 (192..255)
// free-runs the fp32->bf16 conversion of W_obj+W_rel (320 MB) under mega's
// 261 us / 430 GB/s window — no flag interaction, finishes before the
// kernel's natural end. Padded flags (one per 64B line).
// ---------------------------------------------------------------------------
__global__ __launch_bounds__(256, 1)
void mega(const float* __restrict__ xp1, const float* __restrict__ b_ih1,
          const float* __restrict__ Whh1f, const float* __restrict__ b_hh1,
          const float* __restrict__ Wih2f, const float* __restrict__ b_ih2,
          const float* __restrict__ Whh2f, const float* __restrict__ b_hh2,
          short* __restrict__ out1h,   // (36,64,1024) bf16, slot0 = 0
          float* __restrict__ xp2s,    // (35,64,3072) fp32
          short* __restrict__ h2h,     // (36,64,1024) bf16, slot0 = 0
          unsigned* __restrict__ flags1, unsigned* __restrict__ flagsP,
          unsigned* __restrict__ flags2,
          const float* __restrict__ Wobj, const float* __restrict__ Wrel,
          short* __restrict__ Wobj_bf, short* __restrict__ Wrel_bf,
          int do_cvt)
{
    __shared__ __align__(16) short Wl[4 * 3 * 8 * 64 * 8];   // 98304 B
    __shared__ __align__(16) float xch[4][4][3][256];        // 49152 B
    __shared__ __align__(16) short hstage[64][16];           // 2048 B
    const int tid = threadIdx.x;
    const int w  = tid >> 6;
    const int l  = tid & 63;
    const int lr = l & 15, lg = l >> 4;
    const int role = blockIdx.x >> 6;         // 0=GRU1, 1=proj, 2=GRU2, 3=cvt
    const int k    = blockIdx.x & 63;

    if (role == 3) {
        if (do_cvt) {
            const long NC = (long)Vv * Hd / 8;       // 2,560,000 per matrix
            for (long i = (long)k * 256 + tid; i < 2 * NC; i += 64L * 256) {
                if (i < NC) cvt8(Wobj + i * 8, Wobj_bf + i * 8);
                else { const long q = i - NC; cvt8(Wrel + q * 8, Wrel_bf + q * 8); }
            }
        }
        return;
    }

    const int j0 = k * 16;
    const int j  = j0 + lr;
    const float* Wf = (role == 0) ? Whh1f : (role == 1) ? Wih2f : Whh2f;
    const int ldw   = (role == 1) ? (Hd + 512) : Hd;
    const float* bias = (role == 0) ? b_hh1 : (role == 1) ? b_ih2 : b_hh2;

    // stage W slice into LDS, fp32 -> bf16 in-register, fragment-linear
    #pragma unroll
    for (int g = 0; g < 3; ++g)
        #pragma unroll
        for (int ks = 0; ks < 8; ++ks) {
            const float* src = Wf + (size_t)(g * Hd + j) * ldw + w * 256 + ks * 32 + lg * 8;
            *(bf16x8*)(Wl + ((((w * 3 + g) * 8 + ks) * 64) + l) * 8) = pack8(src);
        }

    const float b0 = bias[j], b1 = bias[Hd + j], b2 = bias[2 * Hd + j];
    short* Ab = (role == 2) ? h2h : out1h;

    float bxr = 0.f, bxz = 0.f, bxn = 0.f;
    float hp[4] = {0.f, 0.f, 0.f, 0.f};
    float xr[4], xz[4], xn[4];
    if (role == 0) {
        bxr = b_ih1[j]; bxz = b_ih1[Hd + j]; bxn = b_ih1[2 * Hd + j];
        #pragma unroll
        for (int v = 0; v < 4; ++v) {        // prefetch xp for t=0
            const int b = w * 16 + lg * 4 + v;
            const float* xrow = xp1 + (size_t)b * G3;    // t=0 row = b
            xr[v] = xrow[j]; xz[v] = xrow[Hd + j]; xn[v] = xrow[2 * Hd + j];
        }
    }
    __syncthreads();   // Wl ready

    for (int t = 0; t < TTOT; ++t) {
        if (role == 0)      { if (w == 0) poll_flags(flags1, (unsigned)t); }
        else if (role == 1) { if (w == 0) poll_flags(flags1, (unsigned)(t + 1)); }
        else {
            if (w == 0)      poll_flags(flagsP, (unsigned)(t + 1));
            else if (w == 1) poll_flags(flags2, (unsigned)t);
        }
        __syncthreads();
        asm volatile("" ::: "memory");

        const short* hin = Ab + (size_t)(role == 1 ? t + 1 : t) * (64 * Hd);
        bf16x8 A[4][8];
        #pragma unroll
        for (int mt = 0; mt < 4; ++mt)
            #pragma unroll
            for (int ks = 0; ks < 8; ++ks)
                A[mt][ks] = *(const bf16x8*)(hin + (size_t)(mt * 16 + lr) * Hd
                                             + w * 256 + ks * 32 + lg * 8);
        if (role == 2) {
            #pragma unroll
            for (int v = 0; v < 4; ++v) {
                const int b = w * 16 + lg * 4 + v;
                const float* xrow = xp2s + ((size_t)t * 64 + b) * G3;
                xr[v] = xrow[j]; xz[v] = xrow[Hd + j]; xn[v] = xrow[2 * Hd + j];
            }
        }

        f32x4 acc[4][3] = {};
        #pragma unroll
        for (int ks = 0; ks < 8; ++ks) {
            bf16x8 B0 = *(const bf16x8*)(Wl + ((((w * 3 + 0) * 8 + ks) * 64) + l) * 8);
            bf16x8 B1 = *(const bf16x8*)(Wl + ((((w * 3 + 1) * 8 + ks) * 64) + l) * 8);
            bf16x8 B2 = *(const bf16x8*)(Wl + ((((w * 3 + 2) * 8 + ks) * 64) + l) * 8);
            #pragma unroll
            for (int mt = 0; mt < 4; ++mt) {
                acc[mt][0] = MFMA(A[mt][ks], B0, acc[mt][0]);
                acc[mt][1] = MFMA(A[mt][ks], B1, acc[mt][1]);
                acc[mt][2] = MFMA(A[mt][ks], B2, acc[mt][2]);
            }
        }

        #pragma unroll
        for (int mt = 0; mt < 4; ++mt)
            #pragma unroll
            for (int g = 0; g < 3; ++g)
                *(f32x4*)&xch[w][mt][g][l * 4] = acc[mt][g];
        __syncthreads();
        f32x4 tot[3];
        #pragma unroll
        for (int g = 0; g < 3; ++g) {
            f32x4 t0 = *(const f32x4*)&xch[0][w][g][l * 4];
            f32x4 t1 = *(const f32x4*)&xch[1][w][g][l * 4];
            f32x4 t2 = *(const f32x4*)&xch[2][w][g][l * 4];
            f32x4 t3 = *(const f32x4*)&xch[3][w][g][l * 4];
            tot[g] = (t0 + t1) + (t2 + t3);
        }

        if (role == 1) {
            const float bg[3] = {b0, b1, b2};
            #pragma unroll
            for (int v = 0; v < 4; ++v) {
                const int b = w * 16 + lg * 4 + v;
                #pragma unroll
                for (int g = 0; g < 3; ++g) {
                    union { float f; unsigned u; } cv;
                    cv.f = tot[g][v] + bg[g];
                    __hip_atomic_store(
                        (unsigned*)(xp2s + ((size_t)t * 64 + b) * G3 + g * Hd + j),
                        cv.u, __ATOMIC_RELAXED, __HIP_MEMORY_SCOPE_AGENT);
                }
            }
            __syncthreads();
        } else {
            #pragma unroll
            for (int v = 0; v < 4; ++v) {
                const int b = w * 16 + lg * 4 + v;
                const float rg = 1.f / (1.f + __expf(-(xr[v] + tot[0][v] + b0)));
                const float zg = 1.f / (1.f + __expf(-(xz[v] + tot[1][v] + b1)));
                const float ng = tanhf(xn[v] + rg * (tot[2][v] + b2));
                const float hv = (1.f - zg) * ng + zg * hp[v];
                hp[v] = hv;
                hstage[b][lr] = f2bf(hv);
            }
            if (role == 0) {   // prefetch next round's xp (xp1 static)
                if (t + 1 < Tt) {
                    #pragma unroll
                    for (int v = 0; v < 4; ++v) {
                        const int b = w * 16 + lg * 4 + v;
                        const float* xrow = xp1 + (size_t)((t + 1) * 64 + b) * G3;
                        xr[v] = xrow[j]; xz[v] = xrow[Hd + j]; xn[v] = xrow[2 * Hd + j];
                    }
                } else {
                    #pragma unroll
                    for (int v = 0; v < 4; ++v) { xr[v]=bxr; xz[v]=bxz; xn[v]=bxn; }
                }
            }
            __syncthreads();
            {
                const int b = tid >> 2, part = tid & 3;
                const u64 pv = *(const u64*)&hstage[b][part * 4];
                __hip_atomic_store(
                    (u64*)(Ab + (size_t)(t + 1) * (64 * Hd) + b * Hd + j0 + part * 4),
                    pv, __ATOMIC_RELAXED, __HIP_MEMORY_SCOPE_AGENT);
            }
            __syncthreads();
        }

        if (tid == 0) {
            unsigned* fl = (role == 0) ? flags1 : (role == 1) ? flagsP : flags2;
            __hip_atomic_store(&fl[k * FSTR], (unsigned)(t + 1),
                               __ATOMIC_RELAXED, __HIP_MEMORY_SCOPE_AGENT);
        }
    }
}

// ---------------------------------------------------------------------------
// Logits GEMM (r17 bf16 form): ring 4 / chunk 2, register-lean; fp32
// fallback = r13 form. Blocks 0..312: one W_obj pass computes decode steps
// 0 AND 2. Blocks 313..625: W_rel pass for step 1.
// ---------------------------------------------------------------------------
template<bool WBF16>
__global__ __launch_bounds__(256)
void logits_dual(const short* __restrict__ h2h,
                 const void* __restrict__ Wobj, const float* __restrict__ bobj,
                 const void* __restrict__ Wrel, const float* __restrict__ brel,
                 float* __restrict__ logits3)
{
    const int tid = threadIdx.x;
    const int w = tid >> 6, l = tid & 63;
    const int lr = l & 15, lg = l >> 4;
    const bool dual = blockIdx.x < 313;
    const int nb = dual ? blockIdx.x : blockIdx.x - 313;
    const int tile = nb * 4 + w;
    if (tile >= NTILE) return;
    const int n0 = tile * 16;
    const void* Wo = dual ? Wobj : Wrel;
    const float* bo = dual ? bobj : brel;
    const short* h0 = dual ? (h2h + (size_t)33 * 64 * Hd)
                           : (h2h + (size_t)34 * 64 * Hd);
    const short* hC = h2h + (size_t)35 * 64 * Hd;
    const short* abase = h0 + (size_t)lr * Hd + lg * 8;
    const short* cbase = hC + (size_t)lr * Hd + lg * 8;

    f32x4 accA[4] = {}, accC[4] = {};

    if constexpr (WBF16) {
        const short* wbase = (const short*)Wo + (size_t)(n0 + lr) * Hd + lg * 8;
        bf16x8 wr[4];
        #pragma unroll
        for (int i = 0; i < 4; ++i) wr[i] = *(const bf16x8*)(wbase + i * 32);

        #pragma unroll
        for (int kc = 0; kc < 16; ++kc) {
            bf16x8 Ach[4][2], Cch[4][2];
            #pragma unroll
            for (int u = 0; u < 2; ++u) {
                const int ks = kc * 2 + u;
                #pragma unroll
                for (int mt = 0; mt < 4; ++mt)
                    Ach[mt][u] = *(const bf16x8*)(abase + (size_t)(mt * 16) * Hd + ks * 32);
            }
            if (dual) {
                #pragma unroll
                for (int u = 0; u < 2; ++u) {
                    const int ks = kc * 2 + u;
                    #pragma unroll
                    for (int mt = 0; mt < 4; ++mt)
                        Cch[mt][u] = *(const bf16x8*)(cbase + (size_t)(mt * 16) * Hd + ks * 32);
                }
            }
            #pragma unroll
            for (int u = 0; u < 2; ++u) {
                const int ks = kc * 2 + u;
                const int bi = ks & 3;
                const bf16x8 wv = wr[bi];
                if (ks < 28) wr[bi] = *(const bf16x8*)(wbase + (ks + 4) * 32);
                #pragma unroll
                for (int mt = 0; mt < 4; ++mt) {
                    accA[mt] = MFMA(Ach[mt][u], wv, accA[mt]);
                    if (dual) accC[mt] = MFMA(Cch[mt][u], wv, accC[mt]);
                }
            }
        }
    } else {
        const float* wbase = (const float*)Wo + (size_t)(n0 + lr) * Hd + lg * 8;
        float4 wx[8], wy[8];
        #pragma unroll
        for (int i = 0; i < 8; ++i) {
            wx[i] = *(const float4*)(wbase + i * 32);
            wy[i] = *(const float4*)(wbase + i * 32 + 4);
        }
        #pragma unroll
        for (int kc = 0; kc < 8; ++kc) {
            bf16x8 Ach[4][4], Cch[4][4];
            #pragma unroll
            for (int u = 0; u < 4; ++u) {
                const int ks = kc * 4 + u;
                #pragma unroll
                for (int mt = 0; mt < 4; ++mt)
                    Ach[mt][u] = *(const bf16x8*)(abase + (size_t)(mt * 16) * Hd + ks * 32);
            }
            if (dual) {
                #pragma unroll
                for (int u = 0; u < 4; ++u) {
                    const int ks = kc * 4 + u;
                    #pragma unroll
                    for (int mt = 0; mt < 4; ++mt)
                        Cch[mt][u] = *(const bf16x8*)(cbase + (size_t)(mt * 16) * Hd + ks * 32);
                }
            }
            #pragma unroll
            for (int u = 0; u < 4; ++u) {
                const int ks = kc * 4 + u;
                const int bi = ks & 7;
                const bf16x8 wv = pack2(wx[bi], wy[bi]);
                if (ks < 24) {
                    wx[bi] = *(const float4*)(wbase + (ks + 8) * 32);
                    wy[bi] = *(const float4*)(wbase + (ks + 8) * 32 + 4);
                }
                #pragma unroll
                for (int mt = 0; mt < 4; ++mt) {
                    accA[mt] = MFMA(Ach[mt][u], wv, accA[mt]);
                    if (dual) accC[mt] = MFMA(Cch[mt][u], wv, accC[mt]);
                }
            }
        }
    }

    const float bn = bo[n0 + lr];
    float* lg0 = logits3 + (size_t)(dual ? 0 : 1) * 64 * Vv;
    float* lg2 = logits3 + (size_t)2 * 64 * Vv;
    #pragma unroll
    for (int mt = 0; mt < 4; ++mt)
        #pragma unroll
        for (int v = 0; v < 4; ++v) {
            const size_t row = (size_t)(mt * 16 + lg * 4 + v) * Vv + n0 + lr;
            lg0[row] = accA[mt][v] + bn;
            if (dual) lg2[row] = accC[mt][v] + bn;
        }
}

// ---------------------------------------------------------------------------
// Row log-softmax for all 3 steps: grid 192 = (step, batch).
// ---------------------------------------------------------------------------
__global__ __launch_bounds__(256)
void log_softmax_all(const float* __restrict__ logits3, float* __restrict__ out)
{
    __shared__ float red[4];
    const int step = blockIdx.x >> 6;
    const int b    = blockIdx.x & 63;
    const int tid  = threadIdx.x;
    const float* row = logits3 + ((size_t)step * 64 + b) * Vv;

    float m = -1e30f;
    for (int v = tid; v < Vv; v += 256) m = fmaxf(m, row[v]);
    #pragma unroll
    for (int off = 32; off > 0; off >>= 1) m = fmaxf(m, __shfl_down(m, off, 64));
    if ((tid & 63) == 0) red[tid >> 6] = m;
    __syncthreads();
    m = fmaxf(fmaxf(red[0], red[1]), fmaxf(red[2], red[3]));
    __syncthreads();

    float s = 0.f;
    for (int v = tid; v < Vv; v += 256) s += expf(row[v] - m);
    #pragma unroll
    for (int off = 32; off > 0; off >>= 1) s += __shfl_down(s, off, 64);
    if ((tid & 63) == 0) red[tid >> 6] = s;
    __syncthreads();
    s = red[0] + red[1] + red[2] + red[3];
    const float lse = m + logf(s);

    float* orow = out + ((size_t)b * ML + step) * Vv;
    for (int v = tid; v < Vv; v += 256) orow[v] = row[v] - lse;
}

// ---------------------------------------------------------------------------
extern "C" void kernel_launch(void* const* d_in, const int* in_sizes, int n_in,
                              void* d_out, int out_size, void* d_ws, size_t ws_size,
                              hipStream_t stream)
{
    (void)in_sizes; (void)n_in; (void)out_size;
    const float* vid   = (const float*)d_in[0];
    const float* W_ih1 = (const float*)d_in[1];
    const float* W_hh1 = (const float*)d_in[2];
    const float* b_ih1 = (const float*)d_in[3];
    const float* b_hh1 = (const float*)d_in[4];
    const float* W_ih2 = (const float*)d_in[5];   // (3072,1536); cols 0..1023 used
    const float* W_hh2 = (const float*)d_in[6];
    const float* b_ih2 = (const float*)d_in[7];
    const float* b_hh2 = (const float*)d_in[8];
    const float* W_obj = (const float*)d_in[9];
    const float* b_obj = (const float*)d_in[10];
    const float* W_rel = (const float*)d_in[11];
    const float* b_rel = (const float*)d_in[12];
    float* out = (float*)d_out;

    // workspace carve-up (~180 MB with bf16 W_obj/W_rel)
    char* p = (char*)d_ws;
    short* vid_bf   = (short*)p; p += (size_t)2048 * Dv * 2;        // 8.0 MB
    short* Wih1_bf  = (short*)p; p += (size_t)G3 * Dv * 2;          // 12.6 MB
    unsigned int* flg = (unsigned int*)p; p += 16384;               // padded flags
    short* out1h  = (short*)p; p += (size_t)36 * 64 * Hd * 2;       // 4.7 MB
    short* h2h    = (short*)p; p += (size_t)36 * 64 * Hd * 2;       // 4.7 MB
    float* xp1    = (float*)p; p += (size_t)2048 * G3 * 4;          // 25.2 MB (t-major)
    float* xp2s   = (float*)p; p += (size_t)TTOT * 64 * G3 * 4;     // 27.5 MB
    float* logits3= (float*)p; p += (size_t)ML * 64 * Vv * 4;       // 15.4 MB
    short* Wobj_bf = (short*)p; p += (size_t)Vv * Hd * 2;           // 41.0 MB
    short* Wrel_bf = (short*)p; p += (size_t)Vv * Hd * 2;           // 41.0 MB
    const int use_bf = ((size_t)(p - (char*)d_ws) <= ws_size) ? 1 : 0;

    unsigned* flags1 = flg;                 // 64 flags x stride 16
    unsigned* flagsP = flg + 1024;
    unsigned* flags2 = flg + 2048;

    hipMemsetAsync(flg, 0, 16384, stream);
    hipMemsetAsync(out1h, 0, (size_t)64 * Hd * 2, stream);   // slot 0 = h1(-1)=0
    hipMemsetAsync(h2h,   0, (size_t)64 * Hd * 2, stream);   // slot 0 = h2(-1)=0

    // convert vid + W_ih1 (recurrent/projection weights converted in mega)
    cvt2<<<1280, 256, 0, stream>>>(vid, vid_bf, W_ih1, Wih1_bf);

    // xp1 = vid @ W_ih1^T + b_ih1, written t-major (pure GEMM, 384 blocks)
    gemm_xp1<<<dim3(G3 / 128, 2048 / 128), 256, 0, stream>>>(
        vid_bf, Wih1_bf, b_ih1, xp1);

    // megakernel: encoder + decode GRU steps + hidden W_obj/W_rel conversion
    mega<<<256, 256, 0, stream>>>(
        xp1, b_ih1, W_hh1, b_hh1, W_ih2, b_ih2, W_hh2, b_hh2,
        out1h, xp2s, h2h, flags1, flagsP, flags2,
        W_obj, W_rel, Wobj_bf, Wrel_bf, use_bf);

    // logits for all 3 decode steps (one W_obj pass covers steps 0 and 2)
    if (use_bf)
        logits_dual<true><<<626, 256, 0, stream>>>(
            h2h, (const void*)Wobj_bf, b_obj, (const void*)Wrel_bf, b_rel, logits3);
    else
        logits_dual<false><<<626, 256, 0, stream>>>(
            h2h, (const void*)W_obj, b_obj, (const void*)W_rel, b_rel, logits3);

    // log-softmax -> d_out
    log_softmax_all<<<192, 256, 0, stream>>>(logits3, out);
}